// Round 2
// baseline (77.023 us; speedup 1.0000x reference)
//
#include <hip/hip_runtime.h>
#include <math.h>

#define DD 64

// tanh(a) = (e-1)/(e+1) with e = exp(2a) = exp2(a * 2*log2(e)).
// v_exp_f32 + v_rcp_f32 (~1 ulp each): fixed-point shift ~1e-6, well under 2e-2.
// Clamp keeps e finite (exp2(43.3) ~ 1.1e13) so (e-1)*rcp(e+1) -> 1.0 cleanly.
__device__ __forceinline__ float fast_tanh(float a) {
    a = fminf(fmaxf(a, -15.0f), 15.0f);
    const float e = __builtin_amdgcn_exp2f(a * 2.885390081777927f);
    return (e - 1.0f) * __builtin_amdgcn_rcpf(e + 1.0f);
}

// zl = xi + dot(w, zsh) with 4 independent accumulator chains:
// chain latency 64*4 -> 16*4 cyc; issue-bound at ~128 cyc/wave64.
__device__ __forceinline__ float matvec_row(const float* __restrict__ w,
                                            const float* zsh, float xi) {
    float a0 = xi, a1 = 0.f, a2 = 0.f, a3 = 0.f;
#pragma unroll
    for (int j = 0; j < DD; j += 16) {
        const float4 z0 = *reinterpret_cast<const float4*>(&zsh[j]);
        const float4 z1 = *reinterpret_cast<const float4*>(&zsh[j + 4]);
        const float4 z2 = *reinterpret_cast<const float4*>(&zsh[j + 8]);
        const float4 z3 = *reinterpret_cast<const float4*>(&zsh[j + 12]);
        a0 = fmaf(w[j],      z0.x, a0); a0 = fmaf(w[j + 1],  z0.y, a0);
        a0 = fmaf(w[j + 2],  z0.z, a0); a0 = fmaf(w[j + 3],  z0.w, a0);
        a1 = fmaf(w[j + 4],  z1.x, a1); a1 = fmaf(w[j + 5],  z1.y, a1);
        a1 = fmaf(w[j + 6],  z1.z, a1); a1 = fmaf(w[j + 7],  z1.w, a1);
        a2 = fmaf(w[j + 8],  z2.x, a2); a2 = fmaf(w[j + 9],  z2.y, a2);
        a2 = fmaf(w[j + 10], z2.z, a2); a2 = fmaf(w[j + 11], z2.w, a2);
        a3 = fmaf(w[j + 12], z3.x, a3); a3 = fmaf(w[j + 13], z3.y, a3);
        a3 = fmaf(w[j + 14], z3.z, a3); a3 = fmaf(w[j + 15], z3.w, a3);
    }
    return (a0 + a1) + (a2 + a3);
}

// One wave (64 lanes) per batch row; lane i owns element i and W row i in
// registers. Block = 64 threads = ONE wave: lockstep execution means the LDS
// write/read pattern has no races — no s_barrier needed. wave_barrier is a
// zero-cost compiler scheduling fence keeping ds_write/ds_read in order.
__global__ __launch_bounds__(64)
void tanh_fixed_point(const float* __restrict__ x,
                      const float* __restrict__ W,
                      float* __restrict__ out)
{
    __shared__ float zsh[DD];
    const int lane = threadIdx.x;
    const int b    = blockIdx.x;

    float w[DD];
#pragma unroll
    for (int j = 0; j < DD; j += 4) {
        const float4 v = *reinterpret_cast<const float4*>(W + lane * DD + j);
        w[j] = v.x; w[j + 1] = v.y; w[j + 2] = v.z; w[j + 3] = v.w;
    }

    const float xi = x[b * DD + lane];
    float z = fast_tanh(xi);        // z0 = tanh(x), same as reference

    // Picard iteration z <- tanh(z W^T + x); wave-uniform exit check every 4.
    for (int grp = 0; grp < 64; ++grp) {      // max 256 iterations
        float md = 0.0f;
#pragma unroll
        for (int g = 0; g < 4; ++g) {
            zsh[lane] = z;
            __builtin_amdgcn_wave_barrier();
            const float zl = matvec_row(w, zsh, xi);
            __builtin_amdgcn_wave_barrier();
            const float zn = fast_tanh(zl);
            md = fmaxf(md, fabsf(zn - z));
            z = zn;
        }
#pragma unroll
        for (int off = 32; off; off >>= 1)
            md = fmaxf(md, __shfl_xor(md, off));
        if (md < 1e-6f) break;      // wave-uniform branch
    }

    // Mirror reference: zero rows with ||z - tanh(zW^T+x)||_2 > 1e-4.
    zsh[lane] = z;
    __builtin_amdgcn_wave_barrier();
    const float zl = matvec_row(w, zsh, xi);
    const float g  = z - fast_tanh(zl);
    float s = g * g;
#pragma unroll
    for (int off = 32; off; off >>= 1)
        s += __shfl_xor(s, off);
    if (s > 1e-8f) z = 0.0f;        // sqrt(s) > 1e-4

    out[b * DD + lane] = z;
}

extern "C" void kernel_launch(void* const* d_in, const int* in_sizes, int n_in,
                              void* d_out, int out_size, void* d_ws, size_t ws_size,
                              hipStream_t stream)
{
    const float* x = (const float*)d_in[0];   // [B, 64] fp32
    const float* W = (const float*)d_in[1];   // [64, 64] fp32
    float* out     = (float*)d_out;           // [B, 64] fp32
    const int B = in_sizes[0] / DD;           // 4096
    tanh_fixed_point<<<B, DD, 0, stream>>>(x, W, out);
}